// Round 3
// baseline (377.596 us; speedup 1.0000x reference)
//
#include <hip/hip_runtime.h>

#define DD 1024

typedef float f32x4 __attribute__((ext_vector_type(4)));

// In-register FWHT over 16 values (strides 1,2,4,8 in the register index).
__device__ __forceinline__ void fwht16(float (&v)[16]) {
  #pragma unroll
  for (int h = 1; h < 16; h <<= 1) {
    #pragma unroll
    for (int i = 0; i < 16; ++i) {
      if (!(i & h)) {
        float a = v[i], b = v[i | h];
        v[i]     = a + b;
        v[i | h] = a - b;
      }
    }
  }
}

// Cross-lane butterfly: pairs (lane, lane^mask); lower lane gets a+b, upper a-b.
// masks 1,2 lower to quad-perm DPP (cheap VALU).
__device__ __forceinline__ void shfl_stage(float (&v)[16], int mask, int lane) {
  const float sgn = (lane & mask) ? -1.0f : 1.0f;
  #pragma unroll
  for (int j = 0; j < 16; ++j) {
    float o = __shfl_xor(v[j], mask, 64);
    v[j] = fmaf(sgn, v[j], o);  // lower: o + v = a+b ; upper: o - v = a-b
  }
}

// One wave per row, 16 fp32/lane. No __syncthreads: each wave owns its LDS
// slice; intra-wave LDS ordering is enforced by compiler lgkmcnt waits.
//
// Layout A (contiguous): e = 16*lane + j  -> h=1..8 in-register, h=16,32 via DPP
// Layout B (strided):    e = lane + 64*k  -> h=64..512 in-register
//
// LDS XOR block swizzle: element e = 16L + j stored at float address
//   S(e) = 16L + 4*((j>>2) ^ ((L>>1)&3)) + (j&3)
// A-side: 4x ds_*_b128, conflict-free (bank-group spans all 8 per 8 lanes).
// B-side: addr = 16*lu + 64k + 4*(m^q) + t, q depends only on k&1
//         -> 2 base regs + immediate offsets; 2 lanes/bank (free, m136).
__global__ __launch_bounds__(256) void srht_kernel(
    const float* __restrict__ x,
    const float* __restrict__ signs,
    float* __restrict__ out)
{
  __shared__ float lds[4][DD];
  const int lane = threadIdx.x & 63;
  const int wv   = threadIdx.x >> 6;
  const long row = (long)blockIdx.x * 4 + wv;

  const float* __restrict__ xr = x + row * DD;
  float* __restrict__ orow     = out + row * DD;
  const float* __restrict__ s0 = signs;
  const float* __restrict__ s1 = signs + DD;
  float* buf = lds[wv];

  // B-layout swizzled addressing (element e = lane + 64k):
  const int lu = lane >> 4;          // e>>4 low part
  const int hb = (lane >> 5) & 1;    // (L>>1)&3 contribution from lane
  const int m  = (lane >> 2) & 3;    // j>>2
  const int t  = lane & 3;           // j&3
  const int base_e = 16 * lu + 4 * (m ^ hb) + t;             // k even
  const int base_o = 16 * lu + 4 * (m ^ ((hb + 2) & 3)) + t; // k odd
  // A-layout float4 addressing:
  const int qL    = (lane >> 1) & 3;
  const int abase = 16 * lane;

  // ---- hoist sign1 loads (layout B positions), latency hidden under pass 1
  float s1v[16];
  #pragma unroll
  for (int k = 0; k < 16; ++k) s1v[k] = s1[lane + 64 * k];

  float v[16];

  // ---- load x contiguous (e = 16*lane + j), apply sign0 ----
  {
    const f32x4* xp = (const f32x4*)(xr + 16 * lane);
    const f32x4* sp = (const f32x4*)(s0 + 16 * lane);
    #pragma unroll
    for (int c = 0; c < 4; ++c) {
      f32x4 a = __builtin_nontemporal_load(xp + c);  // read-once stream
      f32x4 s = sp[c];
      v[4 * c + 0] = a.x * s.x;
      v[4 * c + 1] = a.y * s.y;
      v[4 * c + 2] = a.z * s.z;
      v[4 * c + 3] = a.w * s.w;
    }
  }

  // ---- pass 1: A-stages ----
  fwht16(v);               // h = 1,2,4,8
  shfl_stage(v, 1, lane);  // h = 16
  shfl_stage(v, 2, lane);  // h = 32

  // transpose A -> B : swizzled float4 writes (ds_write_b128 x4)
  #pragma unroll
  for (int c = 0; c < 4; ++c) {
    f32x4 w4 = {v[4 * c], v[4 * c + 1], v[4 * c + 2], v[4 * c + 3]};
    *(f32x4*)(buf + abase + 4 * (c ^ qL)) = w4;
  }
  // strided swizzled reads (ds_read_b32 x16, immediate offsets)
  #pragma unroll
  for (int k = 0; k < 16; ++k)
    v[k] = buf[((k & 1) ? base_o : base_e) + 64 * k];

  fwht16(v);               // h = 64,128,256,512  — pass 1 complete

  // ---- between passes: * sign1 * (1/32) ----
  #pragma unroll
  for (int k = 0; k < 16; ++k) v[k] *= s1v[k] * 0.03125f;

  // ---- pass 2: B-stages first (stages commute) ----
  fwht16(v);               // h = 64,128,256,512

  // transpose B -> A
  #pragma unroll
  for (int k = 0; k < 16; ++k)
    buf[((k & 1) ? base_o : base_e) + 64 * k] = v[k];
  #pragma unroll
  for (int c = 0; c < 4; ++c) {
    f32x4 r4 = *(const f32x4*)(buf + abase + 4 * (c ^ qL));
    v[4 * c + 0] = r4.x;
    v[4 * c + 1] = r4.y;
    v[4 * c + 2] = r4.z;
    v[4 * c + 3] = r4.w;
  }

  shfl_stage(v, 1, lane);  // h = 16
  shfl_stage(v, 2, lane);  // h = 32
  fwht16(v);               // h = 1,2,4,8

  // ---- store contiguous, * (1/32), non-temporal ----
  {
    f32x4* op = (f32x4*)(orow + 16 * lane);
    #pragma unroll
    for (int c = 0; c < 4; ++c) {
      f32x4 r;
      r.x = v[4 * c + 0] * 0.03125f;
      r.y = v[4 * c + 1] * 0.03125f;
      r.z = v[4 * c + 2] * 0.03125f;
      r.w = v[4 * c + 3] * 0.03125f;
      __builtin_nontemporal_store(r, op + c);
    }
  }
}

extern "C" void kernel_launch(void* const* d_in, const int* in_sizes, int n_in,
                              void* d_out, int out_size, void* d_ws, size_t ws_size,
                              hipStream_t stream) {
  const float* x     = (const float*)d_in[0];
  const float* signs = (const float*)d_in[1];
  float* out         = (float*)d_out;

  const int rows   = in_sizes[0] / DD;  // 8*8192 = 65536
  const int blocks = rows / 4;          // 4 rows (waves) per 256-thread block

  hipLaunchKernelGGL(srht_kernel, dim3(blocks), dim3(256), 0, stream,
                     x, signs, out);
}

// Round 4
// 130.594 us; speedup vs baseline: 2.8914x; 2.8914x over previous
//
#include <hip/hip_runtime.h>

#define DD 1024

typedef float f32x4 __attribute__((ext_vector_type(4)));

// In-register FWHT over 16 values (strides 1,2,4,8 in the register index).
__device__ __forceinline__ void fwht16(float (&v)[16]) {
  #pragma unroll
  for (int h = 1; h < 16; h <<= 1) {
    #pragma unroll
    for (int i = 0; i < 16; ++i) {
      if (!(i & h)) {
        float a = v[i], b = v[i | h];
        v[i]     = a + b;
        v[i | h] = a - b;
      }
    }
  }
}

// Cross-lane butterfly: pairs (lane, lane^mask); lower lane gets a+b, upper a-b.
// masks 1,2 lower to quad-perm DPP (cheap VALU).
__device__ __forceinline__ void shfl_stage(float (&v)[16], int mask, int lane) {
  const float sgn = (lane & mask) ? -1.0f : 1.0f;
  #pragma unroll
  for (int j = 0; j < 16; ++j) {
    float o = __shfl_xor(v[j], mask, 64);
    v[j] = fmaf(sgn, v[j], o);  // lower: o + v = a+b ; upper: o - v = a-b
  }
}

// One wave per row, 16 fp32/lane. No __syncthreads: each wave owns its LDS
// slice; intra-wave LDS ordering is enforced by compiler lgkmcnt waits.
//
// Layout A (contiguous): e = 16*lane + j  -> h=1..8 in-register, h=16,32 via DPP
// Layout B (strided):    e = lane + 64*k  -> h=64..512 in-register
//
// LDS XOR block swizzle: element e = 16L + j stored at float address
//   S(e) = 16L + 4*((j>>2) ^ ((L>>1)&3)) + (j&3)
// A-side: 4x ds_*_b128, conflict-free. B-side: 2 lanes/bank (free, m136).
//
// NOTE (R3 post-mortem): __builtin_nontemporal_store inflated WRITE_SIZE to
// 664 MB (2.6x ideal) -> 3x regression. Plain cached stores restored.
__global__ __launch_bounds__(256) void srht_kernel(
    const float* __restrict__ x,
    const float* __restrict__ signs,
    float* __restrict__ out)
{
  __shared__ float lds[4][DD];
  const int lane = threadIdx.x & 63;
  const int wv   = threadIdx.x >> 6;
  const long row = (long)blockIdx.x * 4 + wv;

  const float* __restrict__ xr = x + row * DD;
  float* __restrict__ orow     = out + row * DD;
  const float* __restrict__ s0 = signs;
  const float* __restrict__ s1 = signs + DD;
  float* buf = lds[wv];

  // B-layout swizzled addressing (element e = lane + 64k):
  const int lu = lane >> 4;          // e>>4 low part
  const int hb = (lane >> 5) & 1;    // (L>>1)&3 contribution from lane
  const int m  = (lane >> 2) & 3;    // j>>2
  const int t  = lane & 3;           // j&3
  const int base_e = 16 * lu + 4 * (m ^ hb) + t;             // k even
  const int base_o = 16 * lu + 4 * (m ^ ((hb + 2) & 3)) + t; // k odd
  // A-layout float4 addressing:
  const int qL    = (lane >> 1) & 3;
  const int abase = 16 * lane;

  // ---- hoist sign1 loads (layout B positions), latency hidden under pass 1
  float s1v[16];
  #pragma unroll
  for (int k = 0; k < 16; ++k) s1v[k] = s1[lane + 64 * k];

  float v[16];

  // ---- load x contiguous (e = 16*lane + j), apply sign0 ----
  {
    const f32x4* xp = (const f32x4*)(xr + 16 * lane);
    const f32x4* sp = (const f32x4*)(s0 + 16 * lane);
    #pragma unroll
    for (int c = 0; c < 4; ++c) {
      f32x4 a = xp[c];
      f32x4 s = sp[c];
      v[4 * c + 0] = a.x * s.x;
      v[4 * c + 1] = a.y * s.y;
      v[4 * c + 2] = a.z * s.z;
      v[4 * c + 3] = a.w * s.w;
    }
  }

  // ---- pass 1: A-stages ----
  fwht16(v);               // h = 1,2,4,8
  shfl_stage(v, 1, lane);  // h = 16
  shfl_stage(v, 2, lane);  // h = 32

  // transpose A -> B : swizzled float4 writes (ds_write_b128 x4)
  #pragma unroll
  for (int c = 0; c < 4; ++c) {
    f32x4 w4 = {v[4 * c], v[4 * c + 1], v[4 * c + 2], v[4 * c + 3]};
    *(f32x4*)(buf + abase + 4 * (c ^ qL)) = w4;
  }
  // strided swizzled reads (ds_read_b32 x16, immediate offsets)
  #pragma unroll
  for (int k = 0; k < 16; ++k)
    v[k] = buf[((k & 1) ? base_o : base_e) + 64 * k];

  fwht16(v);               // h = 64,128,256,512  — pass 1 complete

  // ---- between passes: * sign1 * (1/32) ----
  #pragma unroll
  for (int k = 0; k < 16; ++k) v[k] *= s1v[k] * 0.03125f;

  // ---- pass 2: B-stages first (stages commute) ----
  fwht16(v);               // h = 64,128,256,512

  // transpose B -> A
  #pragma unroll
  for (int k = 0; k < 16; ++k)
    buf[((k & 1) ? base_o : base_e) + 64 * k] = v[k];
  #pragma unroll
  for (int c = 0; c < 4; ++c) {
    f32x4 r4 = *(const f32x4*)(buf + abase + 4 * (c ^ qL));
    v[4 * c + 0] = r4.x;
    v[4 * c + 1] = r4.y;
    v[4 * c + 2] = r4.z;
    v[4 * c + 3] = r4.w;
  }

  shfl_stage(v, 1, lane);  // h = 16
  shfl_stage(v, 2, lane);  // h = 32
  fwht16(v);               // h = 1,2,4,8

  // ---- store contiguous, * (1/32) ----
  {
    f32x4* op = (f32x4*)(orow + 16 * lane);
    #pragma unroll
    for (int c = 0; c < 4; ++c) {
      f32x4 r;
      r.x = v[4 * c + 0] * 0.03125f;
      r.y = v[4 * c + 1] * 0.03125f;
      r.z = v[4 * c + 2] * 0.03125f;
      r.w = v[4 * c + 3] * 0.03125f;
      op[c] = r;
    }
  }
}

extern "C" void kernel_launch(void* const* d_in, const int* in_sizes, int n_in,
                              void* d_out, int out_size, void* d_ws, size_t ws_size,
                              hipStream_t stream) {
  const float* x     = (const float*)d_in[0];
  const float* signs = (const float*)d_in[1];
  float* out         = (float*)d_out;

  const int rows   = in_sizes[0] / DD;  // 8*8192 = 65536
  const int blocks = rows / 4;          // 4 rows (waves) per 256-thread block

  hipLaunchKernelGGL(srht_kernel, dim3(blocks), dim3(256), 0, stream,
                     x, signs, out);
}

// Round 5
// 124.866 us; speedup vs baseline: 3.0240x; 1.0459x over previous
//
#include <hip/hip_runtime.h>
#include <stdint.h>

#define DD 1024

typedef float f32x4 __attribute__((ext_vector_type(4)));

// In-register FWHT over 16 values (strides 1,2,4,8 in the register index).
__device__ __forceinline__ void fwht16(float (&v)[16]) {
  #pragma unroll
  for (int h = 1; h < 16; h <<= 1) {
    #pragma unroll
    for (int i = 0; i < 16; ++i) {
      if (!(i & h)) {
        float a = v[i], b = v[i | h];
        v[i]     = a + b;
        v[i | h] = a - b;
      }
    }
  }
}

// Cross-lane butterfly: pairs (lane, lane^mask); lower lane gets a+b, upper a-b.
__device__ __forceinline__ void shfl_stage(float (&v)[16], int mask, int lane) {
  const float sgn = (lane & mask) ? -1.0f : 1.0f;
  #pragma unroll
  for (int j = 0; j < 16; ++j) {
    float o = __shfl_xor(v[j], mask, 64);
    v[j] = fmaf(sgn, v[j], o);
  }
}

// DMA one row (4 KB) global -> LDS slot in XOR-swizzled layout
//   S: element e=16M+4n+t  ->  slot[16M + 4*(n ^ ((M>>1)&3)) + t]   (involution)
// global_load_lds writes LDS linearly (lane L -> bytes [16L,16L+16) + 1024c),
// so S is applied to the per-lane GLOBAL source address (m173 pattern):
//   src(c,L) = 256c + 16*(L>>2) + 4*((L&3) ^ ((L>>3)&3))
__device__ __forceinline__ void dma_row(const float* src_row, float* slot, int lane) {
  const int swz = 16 * (lane >> 2) + 4 * ((lane & 3) ^ ((lane >> 3) & 3));
  #pragma unroll
  for (int c = 0; c < 4; ++c) {
    __builtin_amdgcn_global_load_lds(
        (const __attribute__((address_space(1))) void*)(src_row + 256 * c + swz),
        (__attribute__((address_space(3))) void*)(slot + 256 * c),
        16, 0, 0);
  }
}

// Persistent waves, one row per iteration, 16 iters/wave.
// Per wave: 2 LDS slots (double-buffered DMA target; the freed slot is the
// transpose scratch). No __syncthreads (slots are wave-private); DMA
// completion via counted s_waitcnt vmcnt(4) — the 4 newest outstanding VMEM
// ops at loop top are always the previous row's stores.
__global__ __launch_bounds__(256) void srht_kernel(
    const float* __restrict__ x,
    const float* __restrict__ signs,
    float* __restrict__ out,
    int iters, int wstride)
{
  __shared__ float lds[4][2][DD];  // 32 KB/block
  const int lane = threadIdx.x & 63;
  const int wv   = threadIdx.x >> 6;
  const int gw   = blockIdx.x * 4 + wv;

  // B-layout swizzled addressing (element e = lane + 64k):
  const int lu = lane >> 4;
  const int hb = (lane >> 5) & 1;
  const int m  = (lane >> 2) & 3;
  const int t  = lane & 3;
  const int base_e = 16 * lu + 4 * (m ^ hb) + t;             // k even
  const int base_o = 16 * lu + 4 * (m ^ ((hb + 2) & 3)) + t; // k odd
  // A-layout swizzled float4 addressing:
  const int qL    = (lane >> 1) & 3;
  const int abase = 16 * lane;

  // ---- prologue: signs fully into registers (no global loads in the loop
  // except the DMA — any later load's wait would drain the DMA queue) ----
  uint32_t s0m[16];  // sign0 as sign-bit XOR masks (A-layout)
  float    s1v[16];  // sign1 * 1/32                (B-layout)
  {
    const f32x4* sp0 = (const f32x4*)(signs + 16 * lane);
    #pragma unroll
    for (int c = 0; c < 4; ++c) {
      f32x4 s = sp0[c];
      s0m[4 * c + 0] = __float_as_uint(s.x) & 0x80000000u;
      s0m[4 * c + 1] = __float_as_uint(s.y) & 0x80000000u;
      s0m[4 * c + 2] = __float_as_uint(s.z) & 0x80000000u;
      s0m[4 * c + 3] = __float_as_uint(s.w) & 0x80000000u;
    }
    #pragma unroll
    for (int k = 0; k < 16; ++k)
      s1v[k] = signs[DD + lane + 64 * k] * 0.03125f;
  }

  long r = gw;
  dma_row(x + r * (long)DD, lds[wv][0], lane);
  asm volatile("s_waitcnt vmcnt(0)" ::: "memory");  // drain prologue loads + DMA_0

  for (int it = 0; it < iters; ++it) {
    float* slot  = lds[wv][it & 1];        // holds row `it` (staged)
    float* nslot = lds[wv][(it + 1) & 1];  // next DMA target (prev scratch, free)

    // DMA for row `it` complete when only the previous row's 4 stores remain.
    asm volatile("s_waitcnt vmcnt(4)" ::: "memory");

    // ---- consume slot in A-layout (swizzled b128 reads), apply sign0 ----
    float v[16];
    #pragma unroll
    for (int c = 0; c < 4; ++c) {
      f32x4 a = *(const f32x4*)(slot + abase + 4 * (c ^ qL));
      v[4 * c + 0] = __uint_as_float(__float_as_uint(a.x) ^ s0m[4 * c + 0]);
      v[4 * c + 1] = __uint_as_float(__float_as_uint(a.y) ^ s0m[4 * c + 1]);
      v[4 * c + 2] = __uint_as_float(__float_as_uint(a.z) ^ s0m[4 * c + 2]);
      v[4 * c + 3] = __uint_as_float(__float_as_uint(a.w) ^ s0m[4 * c + 3]);
    }

    // ---- issue DMA for row it+1 (in flight under this row's compute) ----
    long rn = (it + 1 < iters) ? (r + wstride) : (long)gw;  // clamp: harmless re-read
    dma_row(x + rn * (long)DD, nslot, lane);

    // ---- pass 1: A-stages ----
    fwht16(v);               // h = 1,2,4,8
    shfl_stage(v, 1, lane);  // h = 16
    shfl_stage(v, 2, lane);  // h = 32

    // transpose A -> B via scratch = slot (just freed)
    #pragma unroll
    for (int c = 0; c < 4; ++c) {
      f32x4 w4 = {v[4 * c], v[4 * c + 1], v[4 * c + 2], v[4 * c + 3]};
      *(f32x4*)(slot + abase + 4 * (c ^ qL)) = w4;
    }
    #pragma unroll
    for (int k = 0; k < 16; ++k)
      v[k] = slot[((k & 1) ? base_o : base_e) + 64 * k];

    fwht16(v);               // h = 64,128,256,512 — pass 1 complete

    // ---- between passes: * sign1 * (1/32) ----
    #pragma unroll
    for (int k = 0; k < 16; ++k) v[k] *= s1v[k];

    // ---- pass 2: B-stages first (stages commute) ----
    fwht16(v);               // h = 64,128,256,512

    // transpose B -> A
    #pragma unroll
    for (int k = 0; k < 16; ++k)
      slot[((k & 1) ? base_o : base_e) + 64 * k] = v[k];
    #pragma unroll
    for (int c = 0; c < 4; ++c) {
      f32x4 r4 = *(const f32x4*)(slot + abase + 4 * (c ^ qL));
      v[4 * c + 0] = r4.x;
      v[4 * c + 1] = r4.y;
      v[4 * c + 2] = r4.z;
      v[4 * c + 3] = r4.w;
    }

    shfl_stage(v, 1, lane);  // h = 16
    shfl_stage(v, 2, lane);  // h = 32
    fwht16(v);               // h = 1,2,4,8

    // ---- store contiguous, * (1/32) ----
    {
      f32x4* op = (f32x4*)(out + r * (long)DD + 16 * lane);
      #pragma unroll
      for (int c = 0; c < 4; ++c) {
        f32x4 o4;
        o4.x = v[4 * c + 0] * 0.03125f;
        o4.y = v[4 * c + 1] * 0.03125f;
        o4.z = v[4 * c + 2] * 0.03125f;
        o4.w = v[4 * c + 3] * 0.03125f;
        op[c] = o4;
      }
    }
    r += wstride;
  }
}

extern "C" void kernel_launch(void* const* d_in, const int* in_sizes, int n_in,
                              void* d_out, int out_size, void* d_ws, size_t ws_size,
                              hipStream_t stream) {
  const float* x     = (const float*)d_in[0];
  const float* signs = (const float*)d_in[1];
  float* out         = (float*)d_out;

  const int rows = in_sizes[0] / DD;  // 65536
  int blocks = 1024;                  // persistent: 4 blocks/CU
  int waves  = blocks * 4;
  if (rows % waves != 0) {            // fallback for odd shapes
    blocks = rows / 4;
    waves  = blocks * 4;
  }
  const int iters = rows / waves;

  hipLaunchKernelGGL(srht_kernel, dim3(blocks), dim3(256), 0, stream,
                     x, signs, out, iters, waves);
}